// Round 4
// baseline (19.501 us; speedup 1.0000x reference)
//
#include <hip/hip_runtime.h>
#include <hip/hip_bf16.h>

#define NUM_USERS   16384
#define NUM_ITEMS   50000
#define EMBED_DIM   64
#define BATCH       16384
#define MAX_FRIENDS 32

// One 64-lane wave per batch element.
// Lane = (g, q): g = lane>>4 selects one of 4 friend rows per iteration,
// q = lane&15 selects a float4 of the 64-dim embedding.
// out[b] = ( denom * <ue,ie> + sum_{f<cnt} w_f * <fe_f, ie> ) / denom
//
// NOTE: the __shfl (ds_bpermute) broadcasts MUST run under full exec mask —
// bpermute from an exec-masked-off lane is undefined (R3 bug). Only the
// row gather + fma are predicated on src < cnt.
__global__ __launch_bounds__(256) void bpr_kernel(
    const int* __restrict__ users,
    const int* __restrict__ items,
    const int* __restrict__ friends,
    const int* __restrict__ fcnt,
    const float* __restrict__ uemb,
    const float* __restrict__ iemb,
    const float* __restrict__ ufr,
    float* __restrict__ out)
{
    const int wave = threadIdx.x >> 6;            // 4 waves per block
    const int lane = threadIdx.x & 63;
    const int b = blockIdx.x * 4 + wave;
    if (b >= BATCH) return;

    const int g = lane >> 4;      // friend sub-group 0..3
    const int q = lane & 15;      // dim quad 0..15

    const int u   = users[b];
    const int it  = items[b];
    const int cnt = fcnt[u];

    const float4 ie4 = *(const float4*)(iemb + (size_t)it * EMBED_DIM + q * 4);
    const float4 ue4 = *(const float4*)(uemb + (size_t)u  * EMBED_DIM + q * 4);

    // Lanes 0..cnt-1: friend id + user_friend weight (2-deep gather chain).
    int   fid = 0;
    float w   = 0.0f;
    if (lane < cnt) {
        fid = friends[(size_t)u * MAX_FRIENDS + lane];
        w   = ufr[(size_t)u * NUM_USERS + fid];
    }

    // Up to 8 iterations, 4 friend rows each. Shuffles run with ALL lanes
    // active; the gather+fma is exec-masked to skip zero-weight friends
    // (E[cnt]=16 -> ~half the row gathers eliminated).
    float4 acc = make_float4(0.f, 0.f, 0.f, 0.f);
    #pragma unroll
    for (int i = 0; i < 8; ++i) {
        const int src = i * 4 + g;            // friend index this lane handles
        const int   idx = __shfl(fid, src);   // full-exec broadcast
        const float wf  = __shfl(w,   src);
        if (src < cnt) {
            const float4 a = *(const float4*)(uemb + (size_t)idx * EMBED_DIM + q * 4);
            acc.x = fmaf(wf, a.x, acc.x);
            acc.y = fmaf(wf, a.y, acc.y);
            acc.z = fmaf(wf, a.z, acc.z);
            acc.w = fmaf(wf, a.w, acc.w);
        }
    }

    float v = acc.x * ie4.x + acc.y * ie4.y + acc.z * ie4.z + acc.w * ie4.w;

    const float denom = (float)max(cnt, 1);
    if (g == 0) {
        const float d = ue4.x * ie4.x + ue4.y * ie4.y + ue4.z * ie4.z + ue4.w * ie4.w;
        v = fmaf(denom, d, v);
    }

    // full-wave 64-lane butterfly reduction
    #pragma unroll
    for (int off = 32; off > 0; off >>= 1)
        v += __shfl_xor(v, off);

    if (lane == 0) out[b] = v / denom;
}

extern "C" void kernel_launch(void* const* d_in, const int* in_sizes, int n_in,
                              void* d_out, int out_size, void* d_ws, size_t ws_size,
                              hipStream_t stream) {
    const int*   users   = (const int*)  d_in[0];
    const int*   items   = (const int*)  d_in[1];
    const int*   friends = (const int*)  d_in[2];
    const int*   fcnt    = (const int*)  d_in[3];
    const float* uemb    = (const float*)d_in[4];
    const float* iemb    = (const float*)d_in[5];
    const float* ufr     = (const float*)d_in[6];
    float*       out     = (float*)d_out;

    const int blocks = BATCH / 4;   // 4 waves (batch elems) per 256-thread block
    bpr_kernel<<<blocks, 256, 0, stream>>>(users, items, friends, fcnt,
                                           uemb, iemb, ufr, out);
}

// Round 5
// 18.495 us; speedup vs baseline: 1.0544x; 1.0544x over previous
//
#include <hip/hip_runtime.h>
#include <hip/hip_bf16.h>

#define NUM_USERS   16384
#define NUM_ITEMS   50000
#define EMBED_DIM   64
#define BATCH       16384
#define MAX_FRIENDS 32

// One 64-lane wave per batch element.
// Lane = (g, q): g = lane>>4 picks one of 4 friend slots per iteration,
// q = lane&15 picks a float4 of the 64-dim embedding.
//
// No cross-lane shuffles at all: each 16-lane group broadcast-loads its own
// friend id (same address -> 1 coalesced txn) and its own weight, so the 8
// iterations are independent memory chains:
//   users -> friends[line-hot] -> { ufr || uemb row } -> fma
// vs the old  users -> friends -> ufr -> bpermute x2 -> uemb -> fma.
__global__ __launch_bounds__(256) void bpr_kernel(
    const int* __restrict__ users,
    const int* __restrict__ items,
    const int* __restrict__ friends,
    const int* __restrict__ fcnt,
    const float* __restrict__ uemb,
    const float* __restrict__ iemb,
    const float* __restrict__ ufr,
    float* __restrict__ out)
{
    const int wave = threadIdx.x >> 6;            // 4 waves per block
    const int lane = threadIdx.x & 63;
    const int b = blockIdx.x * 4 + wave;
    if (b >= BATCH) return;

    const int g = lane >> 4;      // friend sub-group 0..3
    const int q = lane & 15;      // dim quad 0..15

    const int u   = users[b];     // wave-uniform -> scalar load
    const int it  = items[b];
    const int cnt = fcnt[u];

    const float4 ie4 = *(const float4*)(iemb + (size_t)it * EMBED_DIM + q * 4);
    const float4 ue4 = *(const float4*)(uemb + (size_t)u  * EMBED_DIM + q * 4);

    const int* frow = friends + (size_t)u * MAX_FRIENDS;
    const float* urow = ufr + (size_t)u * NUM_USERS;

    // Issue all 8 friend-id broadcast loads up front (2 cache lines total).
    int fid[8];
    #pragma unroll
    for (int i = 0; i < 8; ++i)
        fid[i] = frow[i * 4 + g];             // uniform within group -> broadcast

    float4 acc = make_float4(0.f, 0.f, 0.f, 0.f);
    #pragma unroll
    for (int i = 0; i < 8; ++i) {
        const int src = i * 4 + g;
        if (src < cnt) {
            const float wf = urow[fid[i]];    // group-broadcast, parallel with row load
            const float4 a = *(const float4*)(uemb + (size_t)fid[i] * EMBED_DIM + q * 4);
            acc.x = fmaf(wf, a.x, acc.x);
            acc.y = fmaf(wf, a.y, acc.y);
            acc.z = fmaf(wf, a.z, acc.z);
            acc.w = fmaf(wf, a.w, acc.w);
        }
    }

    float v = acc.x * ie4.x + acc.y * ie4.y + acc.z * ie4.z + acc.w * ie4.w;

    const float denom = (float)max(cnt, 1);
    if (g == 0) {
        const float d = ue4.x * ie4.x + ue4.y * ie4.y + ue4.z * ie4.z + ue4.w * ie4.w;
        v = fmaf(denom, d, v);
    }

    // full-wave 64-lane butterfly reduction
    #pragma unroll
    for (int off = 32; off > 0; off >>= 1)
        v += __shfl_xor(v, off);

    if (lane == 0) out[b] = v / denom;
}

extern "C" void kernel_launch(void* const* d_in, const int* in_sizes, int n_in,
                              void* d_out, int out_size, void* d_ws, size_t ws_size,
                              hipStream_t stream) {
    const int*   users   = (const int*)  d_in[0];
    const int*   items   = (const int*)  d_in[1];
    const int*   friends = (const int*)  d_in[2];
    const int*   fcnt    = (const int*)  d_in[3];
    const float* uemb    = (const float*)d_in[4];
    const float* iemb    = (const float*)d_in[5];
    const float* ufr     = (const float*)d_in[6];
    float*       out     = (float*)d_out;

    const int blocks = BATCH / 4;   // 4 waves (batch elems) per 256-thread block
    bpr_kernel<<<blocks, 256, 0, stream>>>(users, items, friends, fcnt,
                                           uemb, iemb, ufr, out);
}

// Round 6
// 18.287 us; speedup vs baseline: 1.0664x; 1.0114x over previous
//
#include <hip/hip_runtime.h>
#include <hip/hip_bf16.h>

#define NUM_USERS   16384
#define NUM_ITEMS   50000
#define EMBED_DIM   64
#define BATCH       16384
#define MAX_FRIENDS 32

// One 64-lane wave per TWO batch elements (independent chains -> 2x MLP/wave,
// half the waves: 8192 waves = 2048 blocks = 32 waves/CU, single residency
// generation). Lane = (g, q): g = lane>>4 picks a friend chunk, q = lane&15
// picks a float4 of the 64-dim embedding.
// Group g owns friends [8g .. 8g+7]; ids arrive via two int4 loads.
__global__ __launch_bounds__(256) void bpr_kernel(
    const int* __restrict__ users,
    const int* __restrict__ items,
    const int* __restrict__ friends,
    const int* __restrict__ fcnt,
    const float* __restrict__ uemb,
    const float* __restrict__ iemb,
    const float* __restrict__ ufr,
    float* __restrict__ out)
{
    const int wave = threadIdx.x >> 6;            // 4 waves per block
    const int lane = threadIdx.x & 63;
    const int wid  = blockIdx.x * 4 + wave;       // 0..8191
    const int b0 = wid * 2;
    const int b1 = b0 + 1;

    const int g = lane >> 4;      // friend chunk 0..3 (friends 8g..8g+7)
    const int q = lane & 15;      // dim quad 0..15

    const int u0 = users[b0], u1 = users[b1];
    const int i0 = items[b0], i1 = items[b1];
    const int c0 = fcnt[u0],  c1 = fcnt[u1];

    const float4 ieA = *(const float4*)(iemb + (size_t)i0 * EMBED_DIM + q * 4);
    const float4 ieB = *(const float4*)(iemb + (size_t)i1 * EMBED_DIM + q * 4);
    const float4 ueA = *(const float4*)(uemb + (size_t)u0 * EMBED_DIM + q * 4);
    const float4 ueB = *(const float4*)(uemb + (size_t)u1 * EMBED_DIM + q * 4);

    // Friend ids for this group's chunk: two int4 loads per element.
    const int4 fA0 = *(const int4*)(friends + (size_t)u0 * MAX_FRIENDS + g * 8);
    const int4 fA1 = *(const int4*)(friends + (size_t)u0 * MAX_FRIENDS + g * 8 + 4);
    const int4 fB0 = *(const int4*)(friends + (size_t)u1 * MAX_FRIENDS + g * 8);
    const int4 fB1 = *(const int4*)(friends + (size_t)u1 * MAX_FRIENDS + g * 8 + 4);
    const int fidA[8] = { fA0.x, fA0.y, fA0.z, fA0.w, fA1.x, fA1.y, fA1.z, fA1.w };
    const int fidB[8] = { fB0.x, fB0.y, fB0.z, fB0.w, fB1.x, fB1.y, fB1.z, fB1.w };

    const float* urowA = ufr + (size_t)u0 * NUM_USERS;
    const float* urowB = ufr + (size_t)u1 * NUM_USERS;

    float4 accA = make_float4(0.f, 0.f, 0.f, 0.f);
    float4 accB = make_float4(0.f, 0.f, 0.f, 0.f);
    #pragma unroll
    for (int i = 0; i < 8; ++i) {
        const int src = g * 8 + i;                // friend index this lane handles
        if (src < c0) {
            const float wf = urowA[fidA[i]];
            const float4 a = *(const float4*)(uemb + (size_t)fidA[i] * EMBED_DIM + q * 4);
            accA.x = fmaf(wf, a.x, accA.x);
            accA.y = fmaf(wf, a.y, accA.y);
            accA.z = fmaf(wf, a.z, accA.z);
            accA.w = fmaf(wf, a.w, accA.w);
        }
        if (src < c1) {
            const float wf = urowB[fidB[i]];
            const float4 a = *(const float4*)(uemb + (size_t)fidB[i] * EMBED_DIM + q * 4);
            accB.x = fmaf(wf, a.x, accB.x);
            accB.y = fmaf(wf, a.y, accB.y);
            accB.z = fmaf(wf, a.z, accB.z);
            accB.w = fmaf(wf, a.w, accB.w);
        }
    }

    float v0 = accA.x * ieA.x + accA.y * ieA.y + accA.z * ieA.z + accA.w * ieA.w;
    float v1 = accB.x * ieB.x + accB.y * ieB.y + accB.z * ieB.z + accB.w * ieB.w;

    const float d0 = (float)max(c0, 1);
    const float d1 = (float)max(c1, 1);
    if (g == 0) {
        const float pA = ueA.x * ieA.x + ueA.y * ieA.y + ueA.z * ieA.z + ueA.w * ieA.w;
        const float pB = ueB.x * ieB.x + ueB.y * ieB.y + ueB.z * ieB.z + ueB.w * ieB.w;
        v0 = fmaf(d0, pA, v0);
        v1 = fmaf(d1, pB, v1);
    }

    // joint 64-lane butterfly reduction of both partials
    #pragma unroll
    for (int off = 32; off > 0; off >>= 1) {
        v0 += __shfl_xor(v0, off);
        v1 += __shfl_xor(v1, off);
    }

    if (lane == 0) {
        out[b0] = v0 / d0;
        out[b1] = v1 / d1;
    }
}

extern "C" void kernel_launch(void* const* d_in, const int* in_sizes, int n_in,
                              void* d_out, int out_size, void* d_ws, size_t ws_size,
                              hipStream_t stream) {
    const int*   users   = (const int*)  d_in[0];
    const int*   items   = (const int*)  d_in[1];
    const int*   friends = (const int*)  d_in[2];
    const int*   fcnt    = (const int*)  d_in[3];
    const float* uemb    = (const float*)d_in[4];
    const float* iemb    = (const float*)d_in[5];
    const float* ufr     = (const float*)d_in[6];
    float*       out     = (float*)d_out;

    const int blocks = BATCH / 8;   // 4 waves/block, 2 batch elems per wave
    bpr_kernel<<<blocks, 256, 0, stream>>>(users, items, friends, fcnt,
                                           uemb, iemb, ufr, out);
}